// Round 3
// baseline (225.256 us; speedup 1.0000x reference)
//
#include <hip/hip_runtime.h>

#define NPG 28
#define EPG 56
#define ROWS 56      // rows per pair (2 graphs)
#define EDG 112      // edges per pair
#define CH 128
#define LDW 136      // Hs leading dim (bf16 elems), +8 pad

typedef float f32x4 __attribute__((ext_vector_type(4)));
typedef __bf16 bf16x8 __attribute__((ext_vector_type(8)));
typedef unsigned short u16;
typedef u16 u16x8 __attribute__((ext_vector_type(8)));

__device__ __forceinline__ u16 f2bf(float f){
  union { float f; unsigned u; } v; v.f = f;
  unsigned r = (v.u + 0x7fffu + ((v.u >> 16) & 1u)) >> 16;  // RNE
  return (u16)r;
}
__device__ __forceinline__ float bf2f(u16 h){
  union { unsigned u; float f; } v; v.u = ((unsigned)h) << 16;
  return v.f;
}

// Pack W (f32 [128][128], row k, col c) into MFMA B-fragment order, bf16:
// wp[((ct*4+ks)*64 + l)*8 + j] = bf16( W[(l>>4)*8 + ks*32 + j][ct*16 + (l&15)] )
__global__ void pack_w(const float* __restrict__ W, u16* __restrict__ wp){
  int d = blockIdx.x * 256 + threadIdx.x;           // 0..16383
  int j  = d & 7;
  int l  = (d >> 3) & 63;
  int ks = (d >> 9) & 3;
  int ct = d >> 11;
  int k = ((l >> 4) << 3) + (ks << 5) + j;
  int c = (ct << 4) + (l & 15);
  wp[d] = f2bf(W[k * CH + c]);
}

__global__ __launch_bounds__(256, 8)
void gcn_fused(const float* __restrict__ x, const int* __restrict__ ei,
               const float* __restrict__ W, const float* __restrict__ bias,
               const float* __restrict__ ew, const float* __restrict__ gamma,
               const float* __restrict__ beta, float* __restrict__ out,
               const u16* __restrict__ wpack, int npairs)
{
  __shared__ alignas(16) u16 Hs[ROWS][LDW];   // h = xW, bf16 (14.9 KB)
  __shared__ float gbb[3][CH];                // gamma, beta, bias (1.5 KB)
  __shared__ float deg[ROWS];                 // deg -> dinv
  __shared__ int   cnt[ROWS], cnt2[ROWS], rs[ROWS + 1];
  __shared__ int   c_src[EDG];
  __shared__ float c_nrm[EDG];

  const int tid  = threadIdx.x;
  const int lane = tid & 63;
  const int wv   = tid >> 6;
  const int hi   = lane >> 4;
  const int p    = blockIdx.x;                // one pair per block
  const int Etot = npairs * EDG;

  // ---- edge meta + inits (overlap with x loads) ----
  int es = 0, ed = 0; float eww = 0.f;
  if (tid < EDG){
    es  = ei[p * EDG + tid]        - p * ROWS;
    ed  = ei[Etot + p * EDG + tid] - p * ROWS;
    eww = ew[(tid >= EPG) ? (tid - EPG) : tid];
  }
  if (tid < ROWS){ deg[tid] = 1.0f; cnt[tid] = 0; cnt2[tid] = 0; }
  if (tid < CH){
    gbb[0][tid] = gamma[tid]; gbb[1][tid] = beta[tid]; gbb[2][tid] = bias[tid];
  }

  // ---- A-fragments straight from global (also the bf16 residual later) ----
  const int arow = 16 * wv + (lane & 15);
  const int rowc = arow < ROWS ? arow : ROWS - 1;       // clamp pad rows
  const float* xp = x + ((size_t)p * ROWS + rowc) * CH + hi * 8;
  bf16x8 afr[4];
#pragma unroll
  for (int ks = 0; ks < 4; ks++){
    f32x4 lo = *(const f32x4*)(xp + ks * 32);
    f32x4 h4 = *(const f32x4*)(xp + ks * 32 + 4);
    u16x8 t;
    t[0] = f2bf(lo[0]); t[1] = f2bf(lo[1]); t[2] = f2bf(lo[2]); t[3] = f2bf(lo[3]);
    t[4] = f2bf(h4[0]); t[5] = f2bf(h4[1]); t[6] = f2bf(h4[2]); t[7] = f2bf(h4[3]);
    afr[ks] = __builtin_bit_cast(bf16x8, t);
  }

  // ---- GEMM: B-fragments from global wpack (L1-hot across blocks) ----
  f32x4 acc[8];
#pragma unroll
  for (int ct = 0; ct < 8; ct++){
    acc[ct] = (f32x4){0.f, 0.f, 0.f, 0.f};
#pragma unroll
    for (int ks = 0; ks < 4; ks++){
      u16x8 b;
      if (wpack){
        b = ((const u16x8*)wpack)[((ct << 2) + ks) * 64 + lane];
      } else {
#pragma unroll
        for (int j = 0; j < 8; j++){
          int k = hi * 8 + ks * 32 + j;
          int c = ct * 16 + (lane & 15);
          b[j] = f2bf(W[k * CH + c]);
        }
      }
      acc[ct] = __builtin_amdgcn_mfma_f32_16x16x32_bf16(
                  afr[ks], __builtin_bit_cast(bf16x8, b), acc[ct], 0, 0, 0);
    }
  }
  // ---- write h to LDS (transpose to row-major) ----
  {
    int r0 = 16 * wv + (hi << 2);
    int cc = lane & 15;
#pragma unroll
    for (int ct = 0; ct < 8; ct++){
#pragma unroll
      for (int r = 0; r < 4; r++){
        int rr = r0 + r;
        if (rr < ROWS) Hs[rr][16 * ct + cc] = f2bf(acc[ct][r]);
      }
    }
  }
  __syncthreads();   // Hs + deg/cnt init visible

  // ---- degree + indegree ----
  if (tid < EDG){
    atomicAdd(&deg[ed], eww);
    atomicAdd(&cnt[ed], 1);
  }
  __syncthreads();

  // ---- dinv + CSR offsets (wave-0 scan) ----
  if (tid < ROWS) deg[tid] = rsqrtf(deg[tid]);
  if (wv == 0){
    int v = (lane < ROWS) ? cnt[lane] : 0;
#pragma unroll
    for (int off = 1; off < 64; off <<= 1){
      int n = __shfl_up(v, off, 64);
      if (lane >= off) v += n;
    }
    if (lane < ROWS) rs[lane + 1] = v;
    if (lane == 0)   rs[0] = 0;
  }
  __syncthreads();

  // ---- CSR fill with norms ----
  if (tid < EDG){
    float nrm = deg[es] * eww * deg[ed];
    int slot = rs[ed] + atomicAdd(&cnt2[ed], 1);
    c_src[slot] = es;
    c_nrm[slot] = nrm;
  }
  __syncthreads();

  // ---- epilogue: each lane owns its GEMM row; residual from afr regs ----
  if (arow < ROWS){
    const int row = arow;
    const int cb  = hi * 8;                   // chunk base within 32-col group
    float dv = deg[row];
    float d2 = dv * dv;                       // self-loop norm
    float y[4][8];
#pragma unroll
    for (int ks = 0; ks < 4; ks++){
      u16x8 hv = *(const u16x8*)&Hs[row][cb + ks * 32];
      u16x8 xr = __builtin_bit_cast(u16x8, afr[ks]);
      f32x4 b0 = *(const f32x4*)&gbb[2][cb + ks * 32];
      f32x4 b1 = *(const f32x4*)&gbb[2][cb + ks * 32 + 4];
#pragma unroll
      for (int j = 0; j < 8; j++){
        float bb = j < 4 ? b0[j] : b1[j - 4];
        y[ks][j] = bf2f(hv[j]) * d2 + bb + bf2f(xr[j]);
      }
    }
    int s0 = rs[row], s1 = rs[row + 1];
    for (int i = s0; i < s1; i++){
      int sc = c_src[i]; float nm = c_nrm[i];
#pragma unroll
      for (int ks = 0; ks < 4; ks++){
        u16x8 hv = *(const u16x8*)&Hs[sc][cb + ks * 32];
#pragma unroll
        for (int j = 0; j < 8; j++) y[ks][j] += nm * bf2f(hv[j]);
      }
    }
    float sm = 0.f, sq = 0.f;
#pragma unroll
    for (int ks = 0; ks < 4; ks++)
#pragma unroll
      for (int j = 0; j < 8; j++){ sm += y[ks][j]; sq += y[ks][j] * y[ks][j]; }
    sm += __shfl_xor(sm, 16); sq += __shfl_xor(sq, 16);
    sm += __shfl_xor(sm, 32); sq += __shfl_xor(sq, 32);
    float mu   = sm * (1.0f / 128.0f);
    float var  = sq * (1.0f / 128.0f) - mu * mu;
    float rstd = rsqrtf(var + 1e-5f);
    size_t gbase = ((size_t)p * ROWS + row) * CH + cb;
#pragma unroll
    for (int ks = 0; ks < 4; ks++){
      f32x4 g0 = *(const f32x4*)&gbb[0][cb + ks * 32];
      f32x4 g1 = *(const f32x4*)&gbb[0][cb + ks * 32 + 4];
      f32x4 t0 = *(const f32x4*)&gbb[1][cb + ks * 32];
      f32x4 t1 = *(const f32x4*)&gbb[1][cb + ks * 32 + 4];
      f32x4 o0, o1;
#pragma unroll
      for (int j = 0; j < 4; j++){
        o0[j] = fmaxf(0.f, (y[ks][j]     - mu) * rstd * g0[j] + t0[j]);
        o1[j] = fmaxf(0.f, (y[ks][j + 4] - mu) * rstd * g1[j] + t1[j]);
      }
      *(f32x4*)(out + gbase + ks * 32)     = o0;
      *(f32x4*)(out + gbase + ks * 32 + 4) = o1;
    }
  }
}

extern "C" void kernel_launch(void* const* d_in, const int* in_sizes, int n_in,
                              void* d_out, int out_size, void* d_ws, size_t ws_size,
                              hipStream_t stream)
{
  const float* x     = (const float*)d_in[0];
  const int*   ei    = (const int*)d_in[1];
  const float* W     = (const float*)d_in[2];
  const float* bias  = (const float*)d_in[3];
  const float* ew    = (const float*)d_in[4];
  const float* gamma = (const float*)d_in[5];
  const float* beta  = (const float*)d_in[6];
  float* out = (float*)d_out;

  int N = in_sizes[0] / CH;          // 458752
  int npairs = N / ROWS;             // 8192

  u16* wpack = nullptr;
  if (ws_size >= (size_t)(CH * CH * sizeof(u16))){
    wpack = (u16*)d_ws;
    hipLaunchKernelGGL(pack_w, dim3(CH * CH / 256), dim3(256), 0, stream, W, wpack);
  }

  hipLaunchKernelGGL(gcn_fused, dim3(npairs), dim3(256), 0, stream,
                     x, ei, W, bias, ew, gamma, beta, out, wpack, npairs);
}

// Round 4
// 193.704 us; speedup vs baseline: 1.1629x; 1.1629x over previous
//
#include <hip/hip_runtime.h>

#define NPG 28
#define EPG 56
#define ROWS 56      // rows per pair (2 graphs)
#define EDG 112      // edges per pair
#define CH 128
#define LDW 136      // Hs leading dim (bf16 elems), +8 pad

typedef float f32x4 __attribute__((ext_vector_type(4)));
typedef __bf16 bf16x8 __attribute__((ext_vector_type(8)));
typedef unsigned short u16;
typedef u16 u16x8 __attribute__((ext_vector_type(8)));

__device__ __forceinline__ u16 f2bf(float f){
  union { float f; unsigned u; } v; v.f = f;
  unsigned r = (v.u + 0x7fffu + ((v.u >> 16) & 1u)) >> 16;  // RNE
  return (u16)r;
}
__device__ __forceinline__ float bf2f(u16 h){
  union { unsigned u; float f; } v; v.u = ((unsigned)h) << 16;
  return v.f;
}

// Pack W (f32 [128][128], row k, col c) into MFMA B-fragment order, bf16:
// wp[((ct*4+ks)*64 + l)*8 + j] = bf16( W[(l>>4)*8 + ks*32 + j][ct*16 + (l&15)] )
__global__ void pack_w(const float* __restrict__ W, u16* __restrict__ wp){
  int d = blockIdx.x * 256 + threadIdx.x;           // 0..16383
  int j  = d & 7;
  int l  = (d >> 3) & 63;
  int ks = (d >> 9) & 3;
  int ct = d >> 11;
  int k = ((l >> 4) << 3) + (ks << 5) + j;
  int c = (ct << 4) + (l & 15);
  wp[d] = f2bf(W[k * CH + c]);
}

__global__ __launch_bounds__(256, 6)
void gcn_fused(const float* __restrict__ x, const int* __restrict__ ei,
               const float* __restrict__ W, const float* __restrict__ bias,
               const float* __restrict__ ew, const float* __restrict__ gamma,
               const float* __restrict__ beta, float* __restrict__ out,
               const u16* __restrict__ wpack, int npairs)
{
  __shared__ alignas(16) u16 Hs[ROWS][LDW];   // h = xW, bf16 (14.9 KB)
  __shared__ float gbb[3][CH];                // gamma, beta, bias (1.5 KB)
  __shared__ float deg[ROWS];                 // deg -> dinv
  __shared__ int   cnt[ROWS], cnt2[ROWS], rs[ROWS + 1];
  __shared__ int   c_src[EDG];
  __shared__ float c_nrm[EDG];

  const int tid  = threadIdx.x;
  const int lane = tid & 63;
  const int wv   = tid >> 6;
  const int hi   = lane >> 4;
  const int p    = blockIdx.x;                // one pair per block
  const int Etot = npairs * EDG;

  // ---- edge meta + inits (overlap with x loads) ----
  int es = 0, ed = 0; float eww = 0.f;
  if (tid < EDG){
    es  = ei[p * EDG + tid]        - p * ROWS;
    ed  = ei[Etot + p * EDG + tid] - p * ROWS;
    eww = ew[(tid >= EPG) ? (tid - EPG) : tid];
  }
  if (tid < ROWS){ deg[tid] = 1.0f; cnt[tid] = 0; cnt2[tid] = 0; }
  if (tid < CH){
    gbb[0][tid] = gamma[tid]; gbb[1][tid] = beta[tid]; gbb[2][tid] = bias[tid];
  }

  // ---- A-fragments straight from global ----
  const int arow = 16 * wv + (lane & 15);
  const int rowc = arow < ROWS ? arow : ROWS - 1;       // clamp pad rows
  const float* xp = x + ((size_t)p * ROWS + rowc) * CH + hi * 8;

  // ---- GEMM: B-fragments from global wpack (L2-hot across blocks) ----
  f32x4 acc[8];
  {
    bf16x8 afr[4];
#pragma unroll
    for (int ks = 0; ks < 4; ks++){
      f32x4 lo = *(const f32x4*)(xp + ks * 32);
      f32x4 h4 = *(const f32x4*)(xp + ks * 32 + 4);
      u16x8 t;
      t[0] = f2bf(lo[0]); t[1] = f2bf(lo[1]); t[2] = f2bf(lo[2]); t[3] = f2bf(lo[3]);
      t[4] = f2bf(h4[0]); t[5] = f2bf(h4[1]); t[6] = f2bf(h4[2]); t[7] = f2bf(h4[3]);
      afr[ks] = __builtin_bit_cast(bf16x8, t);
    }
#pragma unroll
    for (int ct = 0; ct < 8; ct++){
      acc[ct] = (f32x4){0.f, 0.f, 0.f, 0.f};
#pragma unroll
      for (int ks = 0; ks < 4; ks++){
        u16x8 b;
        if (wpack){
          b = ((const u16x8*)wpack)[((ct << 2) + ks) * 64 + lane];
        } else {
#pragma unroll
          for (int j = 0; j < 8; j++){
            int k = hi * 8 + ks * 32 + j;
            int c = ct * 16 + (lane & 15);
            b[j] = f2bf(W[k * CH + c]);
          }
        }
        acc[ct] = __builtin_amdgcn_mfma_f32_16x16x32_bf16(
                    afr[ks], __builtin_bit_cast(bf16x8, b), acc[ct], 0, 0, 0);
      }
    }
  } // afr dies here

  // ---- write h to LDS (transpose to row-major) ----
  {
    int r0 = 16 * wv + (hi << 2);
    int cc = lane & 15;
#pragma unroll
    for (int ct = 0; ct < 8; ct++){
#pragma unroll
      for (int r = 0; r < 4; r++){
        int rr = r0 + r;
        if (rr < ROWS) Hs[rr][16 * ct + cc] = f2bf(acc[ct][r]);
      }
    }
  }
  __syncthreads();   // Hs + deg/cnt init visible

  // ---- degree + indegree ----
  if (tid < EDG){
    atomicAdd(&deg[ed], eww);
    atomicAdd(&cnt[ed], 1);
  }
  __syncthreads();

  // ---- dinv + CSR offsets (wave-0 scan) ----
  if (tid < ROWS) deg[tid] = rsqrtf(deg[tid]);
  if (wv == 0){
    int v = (lane < ROWS) ? cnt[lane] : 0;
#pragma unroll
    for (int off = 1; off < 64; off <<= 1){
      int n = __shfl_up(v, off, 64);
      if (lane >= off) v += n;
    }
    if (lane < ROWS) rs[lane + 1] = v;
    if (lane == 0)   rs[0] = 0;
  }
  __syncthreads();

  // ---- CSR fill with norms ----
  if (tid < EDG){
    float nrm = deg[es] * eww * deg[ed];
    int slot = rs[ed] + atomicAdd(&cnt2[ed], 1);
    c_src[slot] = es;
    c_nrm[slot] = nrm;
  }
  __syncthreads();

  // ---- epilogue: each lane owns its GEMM row; residual re-read (L2-hot) ----
  if (arow < ROWS){
    const int row = arow;
    const int cb  = hi * 8;                   // chunk base within 32-col group
    float dv = deg[row];
    float d2 = dv * dv;                       // self-loop norm
    const float* xr = x + ((size_t)p * ROWS + row) * CH + cb;
    float y[4][8];
#pragma unroll
    for (int ks = 0; ks < 4; ks++){
      u16x8 hv = *(const u16x8*)&Hs[row][cb + ks * 32];
      f32x4 x0 = *(const f32x4*)(xr + ks * 32);
      f32x4 x1 = *(const f32x4*)(xr + ks * 32 + 4);
      f32x4 b0 = *(const f32x4*)&gbb[2][cb + ks * 32];
      f32x4 b1 = *(const f32x4*)&gbb[2][cb + ks * 32 + 4];
#pragma unroll
      for (int j = 0; j < 4; j++){
        y[ks][j]     = bf2f(hv[j])     * d2 + b0[j] + x0[j];
        y[ks][j + 4] = bf2f(hv[j + 4]) * d2 + b1[j] + x1[j];
      }
    }
    int s0 = rs[row], s1 = rs[row + 1];
    for (int i = s0; i < s1; i++){
      int sc = c_src[i]; float nm = c_nrm[i];
#pragma unroll
      for (int ks = 0; ks < 4; ks++){
        u16x8 hv = *(const u16x8*)&Hs[sc][cb + ks * 32];
#pragma unroll
        for (int j = 0; j < 8; j++) y[ks][j] += nm * bf2f(hv[j]);
      }
    }
    float sm = 0.f, sq = 0.f;
#pragma unroll
    for (int ks = 0; ks < 4; ks++)
#pragma unroll
      for (int j = 0; j < 8; j++){ sm += y[ks][j]; sq += y[ks][j] * y[ks][j]; }
    sm += __shfl_xor(sm, 16); sq += __shfl_xor(sq, 16);
    sm += __shfl_xor(sm, 32); sq += __shfl_xor(sq, 32);
    float mu   = sm * (1.0f / 128.0f);
    float var  = sq * (1.0f / 128.0f) - mu * mu;
    float rstd = rsqrtf(var + 1e-5f);
    size_t gbase = ((size_t)p * ROWS + row) * CH + cb;
#pragma unroll
    for (int ks = 0; ks < 4; ks++){
      f32x4 g0 = *(const f32x4*)&gbb[0][cb + ks * 32];
      f32x4 g1 = *(const f32x4*)&gbb[0][cb + ks * 32 + 4];
      f32x4 t0 = *(const f32x4*)&gbb[1][cb + ks * 32];
      f32x4 t1 = *(const f32x4*)&gbb[1][cb + ks * 32 + 4];
      f32x4 o0, o1;
#pragma unroll
      for (int j = 0; j < 4; j++){
        o0[j] = fmaxf(0.f, (y[ks][j]     - mu) * rstd * g0[j] + t0[j]);
        o1[j] = fmaxf(0.f, (y[ks][j + 4] - mu) * rstd * g1[j] + t1[j]);
      }
      *(f32x4*)(out + gbase + ks * 32)     = o0;
      *(f32x4*)(out + gbase + ks * 32 + 4) = o1;
    }
  }
}

extern "C" void kernel_launch(void* const* d_in, const int* in_sizes, int n_in,
                              void* d_out, int out_size, void* d_ws, size_t ws_size,
                              hipStream_t stream)
{
  const float* x     = (const float*)d_in[0];
  const int*   ei    = (const int*)d_in[1];
  const float* W     = (const float*)d_in[2];
  const float* bias  = (const float*)d_in[3];
  const float* ew    = (const float*)d_in[4];
  const float* gamma = (const float*)d_in[5];
  const float* beta  = (const float*)d_in[6];
  float* out = (float*)d_out;

  int N = in_sizes[0] / CH;          // 458752
  int npairs = N / ROWS;             // 8192

  u16* wpack = nullptr;
  if (ws_size >= (size_t)(CH * CH * sizeof(u16))){
    wpack = (u16*)d_ws;
    hipLaunchKernelGGL(pack_w, dim3(CH * CH / 256), dim3(256), 0, stream, W, wpack);
  }

  hipLaunchKernelGGL(gcn_fused, dim3(npairs), dim3(256), 0, stream,
                     x, ei, W, bias, ew, gamma, beta, out, wpack, npairs);
}

// Round 5
// 164.355 us; speedup vs baseline: 1.3705x; 1.1786x over previous
//
#include <hip/hip_runtime.h>

#define EPG 56
#define ROWS 56      // rows per pair (2 graphs)
#define EDG 112      // edges per pair
#define CH 128
#define LDW 136      // Hs leading dim (bf16 elems), +8 pad

typedef float f32x4 __attribute__((ext_vector_type(4)));
typedef __bf16 bf16x8 __attribute__((ext_vector_type(8)));
typedef unsigned short u16;
typedef u16 u16x8 __attribute__((ext_vector_type(8)));
typedef u16 u16x4 __attribute__((ext_vector_type(4)));

__device__ __forceinline__ u16 f2bf(float f){
  union { float f; unsigned u; } v; v.f = f;
  unsigned r = (v.u + 0x7fffu + ((v.u >> 16) & 1u)) >> 16;  // RNE
  return (u16)r;
}
__device__ __forceinline__ float bf2f(u16 h){
  union { unsigned u; float f; } v; v.u = ((unsigned)h) << 16;
  return v.f;
}

// Pack W (f32 [128][128], row k, col c) into MFMA B-fragment order, bf16:
// wp[((ct*4+ks)*64 + l)*8 + j] = bf16( W[(l>>4)*8 + ks*32 + j][ct*16 + (l&15)] )
__global__ void pack_w(const float* __restrict__ W, u16* __restrict__ wp){
  int d = blockIdx.x * 256 + threadIdx.x;           // 0..16383
  int j  = d & 7;
  int l  = (d >> 3) & 63;
  int ks = (d >> 9) & 3;
  int ct = d >> 11;
  int k = ((l >> 4) << 3) + (ks << 5) + j;
  int c = (ct << 4) + (l & 15);
  wp[d] = f2bf(W[k * CH + c]);
}

__global__ __launch_bounds__(256, 4)
void gcn_fused(const float* __restrict__ x, const int* __restrict__ ei,
               const float* __restrict__ W, const float* __restrict__ bias,
               const float* __restrict__ ew, const float* __restrict__ gamma,
               const float* __restrict__ beta, float* __restrict__ out,
               const u16* __restrict__ wpack, int npairs)
{
  __shared__ alignas(16) u16 Hs[ROWS][LDW];   // h = xW, bf16 (14.9 KB)
  __shared__ float gbb[3][CH];                // gamma, beta, bias
  __shared__ float deg[ROWS];                 // deg -> dinv
  __shared__ int   cnt[ROWS], cnt2[ROWS], rs[ROWS + 1];
  __shared__ int   c_src[EDG];
  __shared__ float c_nrm[EDG];

  const int tid  = threadIdx.x;
  const int lane = tid & 63;
  const int wv   = tid >> 6;
  const int hi   = lane >> 4;
  const int p    = blockIdx.x;                // one pair per block
  const int Etot = npairs * EDG;

  // ---- edge meta + inits (overlap with x loads) ----
  int es = 0, ed = 0; float eww = 0.f;
  if (tid < EDG){
    es  = ei[p * EDG + tid]        - p * ROWS;
    ed  = ei[Etot + p * EDG + tid] - p * ROWS;
    eww = ew[(tid >= EPG) ? (tid - EPG) : tid];
  }
  if (tid < ROWS){ deg[tid] = 1.0f; cnt[tid] = 0; cnt2[tid] = 0; }
  if (tid < CH){
    gbb[0][tid] = gamma[tid]; gbb[1][tid] = beta[tid]; gbb[2][tid] = bias[tid];
  }

  // ---- GEMM: A-frags from global x, B-frags from global wpack ----
  const int arow = 16 * wv + (lane & 15);
  const int rowc = arow < ROWS ? arow : ROWS - 1;       // clamp pad rows
  const float* xp = x + ((size_t)p * ROWS + rowc) * CH + hi * 8;

  f32x4 acc[8];
  {
    bf16x8 afr[4];
#pragma unroll
    for (int ks = 0; ks < 4; ks++){
      f32x4 lo = *(const f32x4*)(xp + ks * 32);
      f32x4 h4 = *(const f32x4*)(xp + ks * 32 + 4);
      u16x8 t;
      t[0] = f2bf(lo[0]); t[1] = f2bf(lo[1]); t[2] = f2bf(lo[2]); t[3] = f2bf(lo[3]);
      t[4] = f2bf(h4[0]); t[5] = f2bf(h4[1]); t[6] = f2bf(h4[2]); t[7] = f2bf(h4[3]);
      afr[ks] = __builtin_bit_cast(bf16x8, t);
    }
#pragma unroll
    for (int ct = 0; ct < 8; ct++){
      acc[ct] = (f32x4){0.f, 0.f, 0.f, 0.f};
#pragma unroll
      for (int ks = 0; ks < 4; ks++){
        u16x8 b;
        if (wpack){
          b = ((const u16x8*)wpack)[((ct << 2) + ks) * 64 + lane];
        } else {
#pragma unroll
          for (int j = 0; j < 8; j++){
            int k = hi * 8 + ks * 32 + j;
            int c = ct * 16 + (lane & 15);
            b[j] = f2bf(W[k * CH + c]);
          }
        }
        acc[ct] = __builtin_amdgcn_mfma_f32_16x16x32_bf16(
                    afr[ks], __builtin_bit_cast(bf16x8, b), acc[ct], 0, 0, 0);
      }
    }
  } // afr dies here

  // ---- write h to LDS (transpose to row-major) ----
  {
    int r0 = 16 * wv + (hi << 2);
    int cc = lane & 15;
#pragma unroll
    for (int ct = 0; ct < 8; ct++){
#pragma unroll
      for (int r = 0; r < 4; r++){
        int rr = r0 + r;
        if (rr < ROWS) Hs[rr][16 * ct + cc] = f2bf(acc[ct][r]);
      }
    }
  }
  __syncthreads();   // Hs + deg/cnt init visible

  // ---- degree + indegree ----
  if (tid < EDG){
    atomicAdd(&deg[ed], eww);
    atomicAdd(&cnt[ed], 1);
  }
  __syncthreads();

  // ---- dinv + CSR offsets (wave-0 scan) ----
  if (tid < ROWS) deg[tid] = rsqrtf(deg[tid]);
  if (wv == 0){
    int v = (lane < ROWS) ? cnt[lane] : 0;
#pragma unroll
    for (int off = 1; off < 64; off <<= 1){
      int n = __shfl_up(v, off, 64);
      if (lane >= off) v += n;
    }
    if (lane < ROWS) rs[lane + 1] = v;
    if (lane == 0)   rs[0] = 0;
  }
  __syncthreads();

  // ---- CSR fill with norms ----
  if (tid < EDG){
    float nrm = deg[es] * eww * deg[ed];
    int slot = rs[ed] + atomicAdd(&cnt2[ed], 1);
    c_src[slot] = es;
    c_nrm[slot] = nrm;
  }
  __syncthreads();

  // ---- epilogue (scalar y0..y3, no aggregates -> no scratch) ----
  // wave owns 2 rows per step: lanes 0-31 -> row 2rp, lanes 32-63 -> row 2rp+1
  const int half = lane >> 5;
  const int l32  = lane & 31;
  const int c0   = l32 * 4;
  for (int rp = wv; rp < ROWS / 2; rp += 4){
    int row = 2 * rp + half;
    float dv = deg[row];
    float d2 = dv * dv;                         // self-loop norm
    size_t gbase = ((size_t)p * ROWS + row) * CH + c0;
    u16x4 hs = *(const u16x4*)&Hs[row][c0];
    f32x4 xr = *(const f32x4*)(x + gbase);      // residual (L2-hot)
    f32x4 bb = *(const f32x4*)&gbb[2][c0];
    float y0 = bf2f(hs[0]) * d2 + bb[0] + xr[0];
    float y1 = bf2f(hs[1]) * d2 + bb[1] + xr[1];
    float y2 = bf2f(hs[2]) * d2 + bb[2] + xr[2];
    float y3 = bf2f(hs[3]) * d2 + bb[3] + xr[3];
    int s0 = rs[row], s1 = rs[row + 1];
    for (int i = s0; i < s1; i++){
      int sc = c_src[i]; float nm = c_nrm[i];
      u16x4 hv = *(const u16x4*)&Hs[sc][c0];
      y0 += nm * bf2f(hv[0]);
      y1 += nm * bf2f(hv[1]);
      y2 += nm * bf2f(hv[2]);
      y3 += nm * bf2f(hv[3]);
    }
    float sm = y0 + y1 + y2 + y3;
    float sq = y0*y0 + y1*y1 + y2*y2 + y3*y3;
#pragma unroll
    for (int m = 1; m < 32; m <<= 1){
      sm += __shfl_xor(sm, m, 32);
      sq += __shfl_xor(sq, m, 32);
    }
    float mu   = sm * (1.0f / 128.0f);
    float var  = sq * (1.0f / 128.0f) - mu * mu;
    float rstd = rsqrtf(var + 1e-5f);
    f32x4 g4 = *(const f32x4*)&gbb[0][c0];
    f32x4 b4 = *(const f32x4*)&gbb[1][c0];
    f32x4 o;
    o[0] = fmaxf(0.f, (y0 - mu) * rstd * g4[0] + b4[0]);
    o[1] = fmaxf(0.f, (y1 - mu) * rstd * g4[1] + b4[1]);
    o[2] = fmaxf(0.f, (y2 - mu) * rstd * g4[2] + b4[2]);
    o[3] = fmaxf(0.f, (y3 - mu) * rstd * g4[3] + b4[3]);
    *(f32x4*)(out + gbase) = o;
  }
}

extern "C" void kernel_launch(void* const* d_in, const int* in_sizes, int n_in,
                              void* d_out, int out_size, void* d_ws, size_t ws_size,
                              hipStream_t stream)
{
  const float* x     = (const float*)d_in[0];
  const int*   ei    = (const int*)d_in[1];
  const float* W     = (const float*)d_in[2];
  const float* bias  = (const float*)d_in[3];
  const float* ew    = (const float*)d_in[4];
  const float* gamma = (const float*)d_in[5];
  const float* beta  = (const float*)d_in[6];
  float* out = (float*)d_out;

  int N = in_sizes[0] / CH;          // 458752
  int npairs = N / ROWS;             // 8192

  u16* wpack = nullptr;
  if (ws_size >= (size_t)(CH * CH * sizeof(u16))){
    wpack = (u16*)d_ws;
    hipLaunchKernelGGL(pack_w, dim3(CH * CH / 256), dim3(256), 0, stream, W, wpack);
  }

  hipLaunchKernelGGL(gcn_fused, dim3(npairs), dim3(256), 0, stream,
                     x, ei, W, bias, ew, gamma, beta, out, wpack, npairs);
}